// Round 5
// baseline (5428.140 us; speedup 1.0000x reference)
//
#include <hip/hip_runtime.h>

#define G 4
#define NBATCH 8
#define HIN 128
#define HD 2324
#define NW 36864
#define NO 36928   // NW + 64 biases
#define NO4 (NO / 4)        // 9232
#define GIN 64
#define GOUT 64
#define HIMG 64
#define WIMG 64
#define CIN 256
#define DSPLIT 16
#define DCHUNK 148          // 15*148 + 104 = 2324; all chunks %4==0
#define OSPLIT 4            // k3: 16 output channels per block
#define K2_REPS 4           // diag: k2 grid.z = DSPLIT*K2_REPS
#define K3_REPS 16          // diag: k3 grid.z = 32*K3_REPS

// K1: h_t[g][d][b] = relu(b1[g][d] + sum_i hyper[b][i] * W1[g][i][d])
__global__ __launch_bounds__(256) void k1_hyper_l1(
    const float* __restrict__ hyper, const float* __restrict__ W1,
    const float* __restrict__ b1, float* __restrict__ h_t) {
  int g = blockIdx.y;
  int d = blockIdx.x * 256 + threadIdx.x;
  if (d >= HD) return;
  const float* W1g = W1 + (size_t)g * HIN * HD + d;
  float bias = b1[g * HD + d];
  float acc[NBATCH];
#pragma unroll
  for (int b = 0; b < NBATCH; ++b) acc[b] = bias;
  for (int i = 0; i < HIN; ++i) {
    float wv = W1g[(size_t)i * HD];
#pragma unroll
    for (int b = 0; b < NBATCH; ++b)
      acc[b] = fmaf(hyper[b * HIN + i], wv, acc[b]);
  }
  float4* hp = (float4*)(h_t + ((size_t)g * HD + d) * 8);
  hp[0] = make_float4(fmaxf(acc[0], 0.f), fmaxf(acc[1], 0.f),
                      fmaxf(acc[2], 0.f), fmaxf(acc[3], 0.f));
  hp[1] = make_float4(fmaxf(acc[4], 0.f), fmaxf(acc[5], 0.f),
                      fmaxf(acc[6], 0.f), fmaxf(acc[7], 0.f));
}

// init: gened[gb][o] = b2[g][o]  (K2 atomically accumulates on top)
__global__ __launch_bounds__(256) void k_init_gened(
    const float* __restrict__ b2, float* __restrict__ gened) {
  const int NF4 = G * NBATCH * NO4;
  int q = blockIdx.x * 256 + threadIdx.x;
  if (q >= NF4) return;
  int gb = q / NO4;
  int g = gb >> 3;
  int o4 = q - gb * NO4;
  ((float4*)gened)[q] = ((const float4*)(b2 + (size_t)g * NO))[o4];
}

#define FMA_D(wv, hoff)                                   \
  {                                                       \
    _Pragma("unroll")                                     \
    for (int b = 0; b < NBATCH; ++b) {                    \
      float hv = hh[(hoff) * 8 + b];                      \
      acc[b].x = fmaf(hv, (wv).x, acc[b].x);              \
      acc[b].y = fmaf(hv, (wv).y, acc[b].y);              \
      acc[b].z = fmaf(hv, (wv).z, acc[b].z);              \
      acc[b].w = fmaf(hv, (wv).w, acc[b].w);              \
    }                                                     \
  }

// K2: target[gb][o] += sum_{d in chunk ds} h[g][b][d] * W2[g][d][o]
// ds = blockIdx.z % DSPLIT (so the same kernel serves the diag launch with
// grid.z = DSPLIT*K2_REPS into a dummy target).
__global__ __launch_bounds__(256) void k2_hyper_l2(
    const float* __restrict__ h_t, const float* __restrict__ W2,
    float* __restrict__ target) {
  int g = blockIdx.y, ds = blockIdx.z & (DSPLIT - 1);
  int o4 = blockIdx.x * 256 + threadIdx.x;
  bool active = (o4 < NO4);
  if (!active) o4 = NO4 - 1;
  const float4* W2g = (const float4*)(W2 + (size_t)g * HD * NO) + o4;
  const float* hg = h_t + (size_t)g * HD * 8;
  int d0 = ds * DCHUNK;
  int d1 = d0 + DCHUNK; if (d1 > HD) d1 = HD;
  int nd = d1 - d0;

  float4 acc[NBATCH];
#pragma unroll
  for (int b = 0; b < NBATCH; ++b) acc[b] = make_float4(0.f, 0.f, 0.f, 0.f);

  const size_t WS = NO4;
  const float4* Wp = W2g + (size_t)d0 * WS;
  float4 w0 = Wp[0], w1 = Wp[WS], w2 = Wp[2 * WS], w3 = Wp[3 * WS];
  int dd = 0;
  for (; dd < nd - 4; dd += 4) {
    const float4* Wn = Wp + (size_t)(dd + 4) * WS;
    float4 n0 = Wn[0], n1 = Wn[WS], n2 = Wn[2 * WS], n3 = Wn[3 * WS];
    const float* hh = hg + (size_t)(d0 + dd) * 8;
    FMA_D(w0, 0) FMA_D(w1, 1) FMA_D(w2, 2) FMA_D(w3, 3)
    w0 = n0; w1 = n1; w2 = n2; w3 = n3;
  }
  {
    const float* hh = hg + (size_t)(d0 + dd) * 8;
    FMA_D(w0, 0) FMA_D(w1, 1) FMA_D(w2, 2) FMA_D(w3, 3)
  }

  if (active) {
#pragma unroll
    for (int b = 0; b < NBATCH; ++b) {
      float* gp = target + (size_t)(g * NBATCH + b) * NO + (size_t)o4 * 4;
      atomicAdd(gp + 0, acc[b].x);
      atomicAdd(gp + 1, acc[b].y);
      atomicAdd(gp + 2, acc[b].z);
      atomicAdd(gp + 3, acc[b].w);
    }
  }
}

// K3: grouped dynamic 3x3 conv (round-4 structure, unchanged math).
// blockIdx.z = rep*32 + (b*4+os); real launch rep==0 -> outbuf = out,
// diag launch grid.z = 32*K3_REPS -> outbuf = dummy.
__global__ __launch_bounds__(256) void k3_conv(
    const float* __restrict__ image, const float* __restrict__ gened,
    float* __restrict__ outbuf) {
  __shared__ float wlds[GIN * 16 * 12];    // 48 KB
  __shared__ float tile[2][18 * 18];
  int t = blockIdx.x;
  int g = blockIdx.y;
  int bos = blockIdx.z & 31;
  int b = bos >> 2, os = bos & 3;
  int gb = g * NBATCH + b;
  int y0 = (t >> 2) << 4, x0 = (t & 3) << 4;
  int tid = threadIdx.x;
  int py = tid >> 4, px = tid & 15;
  int obase = os * 16;

  const float* gw = gened + (size_t)gb * NO;
  const float* imgb = image + ((size_t)b * CIN + g * GIN) * (HIMG * WIMG);

  const float4* wsrc = (const float4*)(gw + obase * 576);
#pragma unroll
  for (int j = 0; j < 9; ++j) {
    int idx = tid + j * 256;
    float4 v = wsrc[idx];
    float vv[4] = {v.x, v.y, v.z, v.w};
#pragma unroll
    for (int e = 0; e < 4; ++e) {
      int f = idx * 4 + e;
      int oo = f / 576;
      int r = f - oo * 576;
      int c = r / 9, k = r - c * 9;
      wlds[(c * 16 + oo) * 12 + k] = vv[e];
    }
  }

  int i0 = tid;
  int iy0 = i0 / 18, ix0 = i0 - iy0 * 18;
  int gy0 = y0 - 1 + iy0, gx0 = x0 - 1 + ix0;
  bool ok0 = (gy0 >= 0 && gy0 < HIMG && gx0 >= 0 && gx0 < WIMG);
  int off0 = gy0 * WIMG + gx0;
  int i1 = tid + 256;
  bool has1 = (i1 < 324);
  int iy1 = i1 / 18, ix1 = i1 - iy1 * 18;
  int gy1 = y0 - 1 + iy1, gx1 = x0 - 1 + ix1;
  bool ok1 = has1 && (gy1 >= 0 && gy1 < HIMG && gx1 >= 0 && gx1 < WIMG);
  int off1 = gy1 * WIMG + gx1;

  float acc[16];
#pragma unroll
  for (int oo = 0; oo < 16; ++oo) acc[oo] = gw[NW + obase + oo];  // bias

  tile[0][i0] = ok0 ? imgb[off0] : 0.0f;
  if (has1) tile[0][i1] = ok1 ? imgb[off1] : 0.0f;
  __syncthreads();

  for (int c = 0; c < GIN; ++c) {
    int cur = c & 1;
    float v0 = 0.0f, v1 = 0.0f;
    if (c + 1 < GIN) {
      const float* ic = imgb + (size_t)(c + 1) * (HIMG * WIMG);
      if (ok0) v0 = ic[off0];
      if (ok1) v1 = ic[off1];
    }
    float p[9];
#pragma unroll
    for (int ky = 0; ky < 3; ++ky)
#pragma unroll
      for (int kx = 0; kx < 3; ++kx)
        p[ky * 3 + kx] = tile[cur][(py + ky) * 18 + (px + kx)];
    const float* wc = &wlds[c * 192];
#pragma unroll
    for (int oo = 0; oo < 16; ++oo) {
      const float* w = wc + oo * 12;
#pragma unroll
      for (int k = 0; k < 9; ++k)
        acc[oo] = fmaf(p[k], w[k], acc[oo]);
    }
    if (c + 1 < GIN) {
      tile[cur ^ 1][i0] = v0;
      if (has1) tile[cur ^ 1][i1] = v1;
    }
    __syncthreads();
  }

  int y = y0 + py, x = x0 + px;
  float* outp = outbuf + ((size_t)b * CIN + g * GOUT + obase) * (HIMG * WIMG)
              + y * WIMG + x;
#pragma unroll
  for (int oo = 0; oo < 16; ++oo)
    outp[(size_t)oo * (HIMG * WIMG)] = acc[oo];
}

extern "C" void kernel_launch(void* const* d_in, const int* in_sizes, int n_in,
                              void* d_out, int out_size, void* d_ws, size_t ws_size,
                              hipStream_t stream) {
  const float* image = (const float*)d_in[0];
  const float* hyper = (const float*)d_in[1];
  const float* W1    = (const float*)d_in[2];
  const float* b1    = (const float*)d_in[3];
  const float* W2    = (const float*)d_in[4];
  const float* b2    = (const float*)d_in[5];
  float* out = (float*)d_out;

  float* h_t         = (float*)d_ws;                          // 74368 f32
  float* gened       = h_t + (size_t)G * HD * 8;              // 1181696 f32
  float* dummy_gened = gened + (size_t)G * NBATCH * NO;       // 1181696 f32
  float* dummy_out   = dummy_gened + (size_t)G * NBATCH * NO; // 8388608 f32

  const int NF4_BLOCKS = (G * NBATCH * NO4 + 255) / 256;

  // --- real pipeline ---
  k1_hyper_l1<<<dim3((HD + 255) / 256, G), 256, 0, stream>>>(hyper, W1, b1, h_t);
  k_init_gened<<<dim3(NF4_BLOCKS), 256, 0, stream>>>(b2, gened);
  k2_hyper_l2<<<dim3((NO4 + 255) / 256, G, DSPLIT), 256, 0, stream>>>(h_t, W2, gened);
  k3_conv<<<dim3(16, G, 32), 256, 0, stream>>>(image, gened, out);

  // --- diagnostic re-launches (same kernels, longer grids, dummy targets) ---
  // k2 x K2_REPS: one dispatch ~4x K2 -> visible in rocprof top-5 with its
  // true hbm_gbps. k3 x K3_REPS: one dispatch ~16x K3 -> dur/16 = true K3.
  k2_hyper_l2<<<dim3((NO4 + 255) / 256, G, DSPLIT * K2_REPS), 256, 0, stream>>>(
      h_t, W2, dummy_gened);
  k3_conv<<<dim3(16, G, 32 * K3_REPS), 256, 0, stream>>>(image, gened, dummy_out);
}

// Round 6
// 4004.172 us; speedup vs baseline: 1.3556x; 1.3556x over previous
//
#include <hip/hip_runtime.h>

#define G 4
#define NBATCH 8
#define HIN 128
#define HD 2324
#define NW 36864
#define NO 36928   // NW + 64 biases
#define NO4 (NO / 4)        // 9232
#define GIN 64
#define GOUT 64
#define HIMG 64
#define WIMG 64
#define CIN 256
#define DSPLIT 16
#define DCHUNK 148          // 15*148 + 104 = 2324
#define K2_REPS 8           // diag
#define K3_REPS 32          // diag

typedef __attribute__((ext_vector_type(8))) short bf16x8;
typedef __attribute__((ext_vector_type(4))) float f32x4;

__device__ inline unsigned short bf16rne(float f) {
  union { float f; unsigned u; } x; x.f = f;
  unsigned r = (x.u + 0x7FFF + ((x.u >> 16) & 1)) >> 16;
  return (unsigned short)r;
}

// K1: h_t[g][d][b] = relu(b1[g][d] + sum_i hyper[b][i] * W1[g][i][d])
__global__ __launch_bounds__(256) void k1_hyper_l1(
    const float* __restrict__ hyper, const float* __restrict__ W1,
    const float* __restrict__ b1, float* __restrict__ h_t) {
  int g = blockIdx.y;
  int d = blockIdx.x * 256 + threadIdx.x;
  if (d >= HD) return;
  const float* W1g = W1 + (size_t)g * HIN * HD + d;
  float bias = b1[g * HD + d];
  float acc[NBATCH];
#pragma unroll
  for (int b = 0; b < NBATCH; ++b) acc[b] = bias;
  for (int i = 0; i < HIN; ++i) {
    float wv = W1g[(size_t)i * HD];
#pragma unroll
    for (int b = 0; b < NBATCH; ++b)
      acc[b] = fmaf(hyper[b * HIN + i], wv, acc[b]);
  }
  float4* hp = (float4*)(h_t + ((size_t)g * HD + d) * 8);
  hp[0] = make_float4(fmaxf(acc[0], 0.f), fmaxf(acc[1], 0.f),
                      fmaxf(acc[2], 0.f), fmaxf(acc[3], 0.f));
  hp[1] = make_float4(fmaxf(acc[4], 0.f), fmaxf(acc[5], 0.f),
                      fmaxf(acc[6], 0.f), fmaxf(acc[7], 0.f));
}

// init: gened[gb][o] = b2[g][o]  (K2 atomically accumulates on top)
__global__ __launch_bounds__(256) void k_init_gened(
    const float* __restrict__ b2, float* __restrict__ gened) {
  const int NF4 = G * NBATCH * NO4;
  int q = blockIdx.x * 256 + threadIdx.x;
  if (q >= NF4) return;
  int gb = q / NO4;
  int g = gb >> 3;
  int o4 = q - gb * NO4;
  ((float4*)gened)[q] = ((const float4*)(b2 + (size_t)g * NO))[o4];
}

#define FMA_D(wv, hoff)                                   \
  {                                                       \
    _Pragma("unroll")                                     \
    for (int b = 0; b < NBATCH; ++b) {                    \
      float hv = hh[(hoff) * 8 + b];                      \
      acc[b].x = fmaf(hv, (wv).x, acc[b].x);              \
      acc[b].y = fmaf(hv, (wv).y, acc[b].y);              \
      acc[b].z = fmaf(hv, (wv).z, acc[b].z);              \
      acc[b].w = fmaf(hv, (wv).w, acc[b].w);              \
    }                                                     \
  }

// K2: target[gb][o] += sum_{d in chunk ds} h[g][b][d] * W2[g][d][o]
__global__ __launch_bounds__(256) void k2_hyper_l2(
    const float* __restrict__ h_t, const float* __restrict__ W2,
    float* __restrict__ target) {
  int g = blockIdx.y, ds = blockIdx.z & (DSPLIT - 1);
  int o4 = blockIdx.x * 256 + threadIdx.x;
  bool active = (o4 < NO4);
  if (!active) o4 = NO4 - 1;
  const float4* W2g = (const float4*)(W2 + (size_t)g * HD * NO) + o4;
  const float* hg = h_t + (size_t)g * HD * 8;
  int d0 = ds * DCHUNK;
  int d1 = d0 + DCHUNK; if (d1 > HD) d1 = HD;
  int nd = d1 - d0;

  float4 acc[NBATCH];
#pragma unroll
  for (int b = 0; b < NBATCH; ++b) acc[b] = make_float4(0.f, 0.f, 0.f, 0.f);

  const size_t WS = NO4;
  const float4* Wp = W2g + (size_t)d0 * WS;
  float4 w0 = Wp[0], w1 = Wp[WS], w2 = Wp[2 * WS], w3 = Wp[3 * WS];
  int dd = 0;
  for (; dd < nd - 4; dd += 4) {
    const float4* Wn = Wp + (size_t)(dd + 4) * WS;
    float4 n0 = Wn[0], n1 = Wn[WS], n2 = Wn[2 * WS], n3 = Wn[3 * WS];
    const float* hh = hg + (size_t)(d0 + dd) * 8;
    FMA_D(w0, 0) FMA_D(w1, 1) FMA_D(w2, 2) FMA_D(w3, 3)
    w0 = n0; w1 = n1; w2 = n2; w3 = n3;
  }
  {
    const float* hh = hg + (size_t)(d0 + dd) * 8;
    FMA_D(w0, 0) FMA_D(w1, 1) FMA_D(w2, 2) FMA_D(w3, 3)
  }

  if (active) {
#pragma unroll
    for (int b = 0; b < NBATCH; ++b) {
      float* gp = target + (size_t)(g * NBATCH + b) * NO + (size_t)o4 * 4;
      atomicAdd(gp + 0, acc[b].x);
      atomicAdd(gp + 1, acc[b].y);
      atomicAdd(gp + 2, acc[b].z);
      atomicAdd(gp + 3, acc[b].w);
    }
  }
}

// wprep: wbf[gb][k][o][c] = bf16(gened[gb][o*576 + c*9 + k])   (A-fragments)
__global__ __launch_bounds__(256) void k_wprep(
    const float* __restrict__ gened, short* __restrict__ wbf) {
  int gb = blockIdx.y;
  int q = blockIdx.x * 256 + threadIdx.x;     // [0, 36864)
  int c = q & 63, rest = q >> 6;
  int o = rest & 63, k = rest >> 6;           // k 0..8
  float v = gened[(size_t)gb * NO + o * 576 + c * 9 + k];
  wbf[(size_t)gb * 9 * 4096 + q] = (short)bf16rne(v);  // q == k*4096+o*64+c
}

// bias: bias_f[gb*64+o] = gened[gb][NW+o]
__global__ __launch_bounds__(256) void k_bias(
    const float* __restrict__ gened, float* __restrict__ bias_f) {
  int i = blockIdx.x * 256 + threadIdx.x;
  if (i >= G * NBATCH * GOUT) return;
  int gb = i >> 6, o = i & 63;
  bias_f[i] = gened[(size_t)gb * NO + NW + o];
}

// iprep: imgt[gb][y+1][x+1][c] = bf16(image[b][g*64+c][y][x]); border pre-zeroed.
// block = one image row of one (g,b): transpose via LDS.
__global__ __launch_bounds__(256) void k_iprep(
    const float* __restrict__ image, short* __restrict__ imgt) {
  __shared__ float lds[64 * 65];
  int y = blockIdx.x, g = blockIdx.y, b = blockIdx.z;
  int gb = g * NBATCH + b;
  int tid = threadIdx.x;
  int p = tid & 63, cg = tid >> 6;
#pragma unroll
  for (int i = 0; i < 16; ++i) {
    int c = cg * 16 + i;
    lds[p * 65 + c] = image[((size_t)b * CIN + g * GIN + c) * 4096 + y * 64 + p];
  }
  __syncthreads();
  int p2 = tid >> 2, cq = tid & 3;
  unsigned short tmp[16];
#pragma unroll
  for (int i = 0; i < 16; ++i) tmp[i] = bf16rne(lds[p2 * 65 + cq * 16 + i]);
  short* dst = imgt + (((size_t)gb * 66 + y + 1) * 66 + (p2 + 1)) * 64 + cq * 16;
  *(uint4*)dst = *(uint4*)&tmp[0];
  *(uint4*)(dst + 8) = *(uint4*)&tmp[8];
}

// K3-MFMA: out[b][g*64+o][y][x] = sum_{tap,c} w[o][c,tap] * img[c][y+dy-1][x+dx-1]
// 32 GEMMs M=64,N=4096,K=576 as 9 shifts x 2 c-tiles of 16x16x32 bf16 MFMA.
// Wave = one image row y; 4x4 C-frags (all 64 o x 64 x); 1-deep reg prefetch.
__global__ __launch_bounds__(256) void k3_mfma(
    const short* __restrict__ wbf, const short* __restrict__ imgt,
    const float* __restrict__ bias_f, float* __restrict__ outbuf) {
  int g = blockIdx.y, b = blockIdx.z;
  int gb = g * NBATCH + b;
  int ygrp = blockIdx.x & 15;
  int tid = threadIdx.x;
  int w = tid >> 6, l = tid & 63;
  int y = ygrp * 4 + w;
  int lo = l & 15;   // A row (o), B col (x), D col
  int hi = l >> 4;   // k-chunk selector; D row-block

  const short* wgb = wbf + (size_t)gb * 9 * 4096;   // [tap][o][c]
  const short* ibase = imgt + (((size_t)gb * 66 + y) * 66 + lo) * 64 + hi * 8;

  f32x4 acc[4][4] = {};
  bf16x8 a0[4], b0[4], a1[4], b1[4];

#define LA(dst, ks) { int s_ = (ks) >> 1, h_ = (ks) & 1;                      \
    const short* p_ = wgb + (size_t)s_ * 4096 + lo * 64 + h_ * 32 + hi * 8;   \
    _Pragma("unroll") for (int m_ = 0; m_ < 4; ++m_)                          \
      dst[m_] = *(const bf16x8*)(p_ + m_ * 1024); }
#define LB(dst, ks) { int s_ = (ks) >> 1, h_ = (ks) & 1;                      \
    int dy_ = s_ / 3, dx_ = s_ - 3 * dy_;                                     \
    const short* p_ = ibase + ((size_t)dy_ * 66 + dx_) * 64 + h_ * 32;        \
    _Pragma("unroll") for (int n_ = 0; n_ < 4; ++n_)                          \
      dst[n_] = *(const bf16x8*)(p_ + n_ * 1024); }
#define MM(aa, bb) { _Pragma("unroll") for (int m_ = 0; m_ < 4; ++m_)         \
    _Pragma("unroll") for (int n_ = 0; n_ < 4; ++n_)                          \
      acc[m_][n_] = __builtin_amdgcn_mfma_f32_16x16x32_bf16(                  \
          aa[m_], bb[n_], acc[m_][n_], 0, 0, 0); }

  LA(a0, 0) LB(b0, 0)
#pragma unroll
  for (int it = 0; it < 9; ++it) {
    LA(a1, 2 * it + 1) LB(b1, 2 * it + 1)
    MM(a0, b0)
    if (it < 8) { LA(a0, 2 * it + 2) LB(b0, 2 * it + 2) }
    MM(a1, b1)
  }

  float* op = outbuf + ((size_t)b * CIN + g * GOUT) * 4096 + y * 64;
#pragma unroll
  for (int m = 0; m < 4; ++m)
#pragma unroll
    for (int j = 0; j < 4; ++j) {
      int o = m * 16 + hi * 4 + j;
      float bias = bias_f[gb * 64 + o];
#pragma unroll
      for (int n = 0; n < 4; ++n)
        op[(size_t)o * 4096 + n * 16 + lo] = acc[m][n][j] + bias;
    }
#undef LA
#undef LB
#undef MM
}

extern "C" void kernel_launch(void* const* d_in, const int* in_sizes, int n_in,
                              void* d_out, int out_size, void* d_ws, size_t ws_size,
                              hipStream_t stream) {
  const float* image = (const float*)d_in[0];
  const float* hyper = (const float*)d_in[1];
  const float* W1    = (const float*)d_in[2];
  const float* b1    = (const float*)d_in[3];
  const float* W2    = (const float*)d_in[4];
  const float* b2    = (const float*)d_in[5];
  float* out = (float*)d_out;

  float* h_t    = (float*)d_ws;                                // 74368 f32
  float* gened  = h_t + (size_t)G * HD * 8;                    // 1181696 f32
  float* bias_f = gened + (size_t)G * NBATCH * NO;             // 2048 f32
  short* wbf    = (short*)(bias_f + G * NBATCH * GOUT);        // 1179648 bf16
  short* imgt   = wbf + (size_t)G * NBATCH * 9 * 4096;         // 8921088 bf16
  float* dummy_gened = (float*)(imgt + (size_t)G * NBATCH * 66 * 66 * 64);
  float* dummy_out   = dummy_gened + (size_t)G * NBATCH * NO;

  const size_t IMGT_BYTES = (size_t)G * NBATCH * 66 * 66 * 64 * sizeof(short);
  const int NF4_BLOCKS = (G * NBATCH * NO4 + 255) / 256;

  // --- real pipeline ---
  hipMemsetAsync(imgt, 0, IMGT_BYTES, stream);                 // zero halo
  k_iprep<<<dim3(64, G, NBATCH), 256, 0, stream>>>(image, imgt);
  k1_hyper_l1<<<dim3((HD + 255) / 256, G), 256, 0, stream>>>(hyper, W1, b1, h_t);
  k_init_gened<<<dim3(NF4_BLOCKS), 256, 0, stream>>>(b2, gened);
  k2_hyper_l2<<<dim3((NO4 + 255) / 256, G, DSPLIT), 256, 0, stream>>>(h_t, W2, gened);
  k_wprep<<<dim3(144, G * NBATCH), 256, 0, stream>>>(gened, wbf);
  k_bias<<<dim3((G * NBATCH * GOUT + 255) / 256), 256, 0, stream>>>(gened, bias_f);
  k3_mfma<<<dim3(16, G, NBATCH), 256, 0, stream>>>(wbf, imgt, bias_f, out);

  // --- diagnostic re-launches (dummy targets; stripped next round) ---
  k2_hyper_l2<<<dim3((NO4 + 255) / 256, G, DSPLIT * K2_REPS), 256, 0, stream>>>(
      h_t, W2, dummy_gened);
  k3_mfma<<<dim3(16 * K3_REPS, G, NBATCH), 256, 0, stream>>>(wbf, imgt, bias_f, dummy_out);
}

// Round 7
// 476.762 us; speedup vs baseline: 11.3854x; 8.3987x over previous
//
#include <hip/hip_runtime.h>

#define G 4
#define NBATCH 8
#define HIN 128
#define HD 2324
#define NW 36864
#define NO 36928   // NW + 64 biases
#define NO4 (NO / 4)        // 9232
#define GIN 64
#define GOUT 64
#define HIMG 64
#define WIMG 64
#define CIN 256
#define DSPLIT 16
#define DCHUNK 148          // 15*148 + 104 = 2324

typedef __attribute__((ext_vector_type(8))) short bf16x8;
typedef __attribute__((ext_vector_type(4))) float f32x4;

__device__ inline unsigned short bf16rne(float f) {
  union { float f; unsigned u; } x; x.f = f;
  unsigned r = (x.u + 0x7FFF + ((x.u >> 16) & 1)) >> 16;
  return (unsigned short)r;
}

// K1: h_t[g][d][b] = relu(b1[g][d] + sum_i hyper[b][i] * W1[g][i][d])
__global__ __launch_bounds__(256) void k1_hyper_l1(
    const float* __restrict__ hyper, const float* __restrict__ W1,
    const float* __restrict__ b1, float* __restrict__ h_t) {
  int g = blockIdx.y;
  int d = blockIdx.x * 256 + threadIdx.x;
  if (d >= HD) return;
  const float* W1g = W1 + (size_t)g * HIN * HD + d;
  float bias = b1[g * HD + d];
  float acc[NBATCH];
#pragma unroll
  for (int b = 0; b < NBATCH; ++b) acc[b] = bias;
  for (int i = 0; i < HIN; ++i) {
    float wv = W1g[(size_t)i * HD];
#pragma unroll
    for (int b = 0; b < NBATCH; ++b)
      acc[b] = fmaf(hyper[b * HIN + i], wv, acc[b]);
  }
  float4* hp = (float4*)(h_t + ((size_t)g * HD + d) * 8);
  hp[0] = make_float4(fmaxf(acc[0], 0.f), fmaxf(acc[1], 0.f),
                      fmaxf(acc[2], 0.f), fmaxf(acc[3], 0.f));
  hp[1] = make_float4(fmaxf(acc[4], 0.f), fmaxf(acc[5], 0.f),
                      fmaxf(acc[6], 0.f), fmaxf(acc[7], 0.f));
}

// init: gened[gb][o] = b2[g][o]  (K2 atomically accumulates on top)
__global__ __launch_bounds__(256) void k_init_gened(
    const float* __restrict__ b2, float* __restrict__ gened) {
  const int NF4 = G * NBATCH * NO4;
  int q = blockIdx.x * 256 + threadIdx.x;
  if (q >= NF4) return;
  int gb = q / NO4;
  int g = gb >> 3;
  int o4 = q - gb * NO4;
  ((float4*)gened)[q] = ((const float4*)(b2 + (size_t)g * NO))[o4];
}

#define FMA_D(wv, hoff)                                   \
  {                                                       \
    _Pragma("unroll")                                     \
    for (int b = 0; b < NBATCH; ++b) {                    \
      float hv = hh[(hoff) * 8 + b];                      \
      acc[b].x = fmaf(hv, (wv).x, acc[b].x);              \
      acc[b].y = fmaf(hv, (wv).y, acc[b].y);              \
      acc[b].z = fmaf(hv, (wv).z, acc[b].z);              \
      acc[b].w = fmaf(hv, (wv).w, acc[b].w);              \
    }                                                     \
  }

// K2: gened[gb][o] += sum_{d in chunk ds} h[g][b][d] * W2[g][d][o]
__global__ __launch_bounds__(256) void k2_hyper_l2(
    const float* __restrict__ h_t, const float* __restrict__ W2,
    float* __restrict__ target) {
  int g = blockIdx.y, ds = blockIdx.z & (DSPLIT - 1);
  int o4 = blockIdx.x * 256 + threadIdx.x;
  bool active = (o4 < NO4);
  if (!active) o4 = NO4 - 1;
  const float4* W2g = (const float4*)(W2 + (size_t)g * HD * NO) + o4;
  const float* hg = h_t + (size_t)g * HD * 8;
  int d0 = ds * DCHUNK;
  int d1 = d0 + DCHUNK; if (d1 > HD) d1 = HD;
  int nd = d1 - d0;

  float4 acc[NBATCH];
#pragma unroll
  for (int b = 0; b < NBATCH; ++b) acc[b] = make_float4(0.f, 0.f, 0.f, 0.f);

  const size_t WS = NO4;
  const float4* Wp = W2g + (size_t)d0 * WS;
  float4 w0 = Wp[0], w1 = Wp[WS], w2 = Wp[2 * WS], w3 = Wp[3 * WS];
  int dd = 0;
  for (; dd < nd - 4; dd += 4) {
    const float4* Wn = Wp + (size_t)(dd + 4) * WS;
    float4 n0 = Wn[0], n1 = Wn[WS], n2 = Wn[2 * WS], n3 = Wn[3 * WS];
    const float* hh = hg + (size_t)(d0 + dd) * 8;
    FMA_D(w0, 0) FMA_D(w1, 1) FMA_D(w2, 2) FMA_D(w3, 3)
    w0 = n0; w1 = n1; w2 = n2; w3 = n3;
  }
  {
    const float* hh = hg + (size_t)(d0 + dd) * 8;
    FMA_D(w0, 0) FMA_D(w1, 1) FMA_D(w2, 2) FMA_D(w3, 3)
  }

  if (active) {
#pragma unroll
    for (int b = 0; b < NBATCH; ++b) {
      float* gp = target + (size_t)(g * NBATCH + b) * NO + (size_t)o4 * 4;
      atomicAdd(gp + 0, acc[b].x);
      atomicAdd(gp + 1, acc[b].y);
      atomicAdd(gp + 2, acc[b].z);
      atomicAdd(gp + 3, acc[b].w);
    }
  }
}

// wprep: wbf[gb][k][o][c] = bf16(gened[gb][o*576 + c*9 + k])   (A-fragments)
// block x==144 extracts the bias instead.
__global__ __launch_bounds__(256) void k_wprep(
    const float* __restrict__ gened, short* __restrict__ wbf,
    float* __restrict__ bias_f) {
  int gb = blockIdx.y;
  if (blockIdx.x == 144) {
    int tid = threadIdx.x;
    if (tid < GOUT) bias_f[gb * GOUT + tid] = gened[(size_t)gb * NO + NW + tid];
    return;
  }
  int q = blockIdx.x * 256 + threadIdx.x;     // [0, 36864)
  int c = q & 63, rest = q >> 6;
  int o = rest & 63, k = rest >> 6;           // k 0..8
  float v = gened[(size_t)gb * NO + o * 576 + c * 9 + k];
  wbf[(size_t)gb * 9 * 4096 + q] = (short)bf16rne(v);  // q == k*4096+o*64+c
}

// iprep: imgt[gb][y+1][x+1][c] = bf16(image[b][g*64+c][y][x]);
// halo rows/cols written in-kernel (no separate memset).
// grid.x = 66 dest rows; row 0/65 = zero rows; else transpose via LDS.
__global__ __launch_bounds__(256) void k_iprep(
    const float* __restrict__ image, short* __restrict__ imgt) {
  int row = blockIdx.x;                       // dest row 0..65
  int g = blockIdx.y, b = blockIdx.z;
  int gb = g * NBATCH + b;
  int tid = threadIdx.x;
  short* rowp = imgt + ((size_t)gb * 66 + row) * 66 * 64;
  if (row == 0 || row == 65) {                // top/bottom halo row
    uint4 z = {0, 0, 0, 0};
    uint4* p = (uint4*)rowp;                  // 66*64*2B = 528 uint4
#pragma unroll
    for (int i = 0; i < 3; ++i) {
      int idx = tid + i * 256;
      if (idx < 528) p[idx] = z;
    }
    return;
  }
  int y = row - 1;
  __shared__ float lds[64 * 65];
  int p = tid & 63, cg = tid >> 6;
#pragma unroll
  for (int i = 0; i < 16; ++i) {
    int c = cg * 16 + i;
    lds[p * 65 + c] = image[((size_t)b * CIN + g * GIN + c) * 4096 + y * 64 + p];
  }
  __syncthreads();
  int p2 = tid >> 2, cq = tid & 3;
  unsigned short tmp[16];
#pragma unroll
  for (int i = 0; i < 16; ++i) tmp[i] = bf16rne(lds[p2 * 65 + cq * 16 + i]);
  short* dst = rowp + (p2 + 1) * 64 + cq * 16;
  *(uint4*)dst = *(uint4*)&tmp[0];
  *(uint4*)(dst + 8) = *(uint4*)&tmp[8];
  // side halo: col 0 and col 65 (64 bf16 = 128 B each)
  if (tid < 16) {
    ((uint2*)rowp)[tid] = make_uint2(0, 0);
  } else if (tid < 32) {
    ((uint2*)(rowp + 65 * 64))[tid - 16] = make_uint2(0, 0);
  }
}

// K3-MFMA: 32 GEMMs M=64,N=4096,K=576 as 9 shifts x 2 c-tiles of
// 16x16x32 bf16 MFMA. Wave = one image row y; 4x4 C-frags; 1-deep prefetch.
__global__ __launch_bounds__(256) void k3_mfma(
    const short* __restrict__ wbf, const short* __restrict__ imgt,
    const float* __restrict__ bias_f, float* __restrict__ outbuf) {
  int g = blockIdx.y, b = blockIdx.z;
  int gb = g * NBATCH + b;
  int ygrp = blockIdx.x & 15;
  int tid = threadIdx.x;
  int w = tid >> 6, l = tid & 63;
  int y = ygrp * 4 + w;
  int lo = l & 15;   // A row (o), B col (x), D col
  int hi = l >> 4;   // k-chunk selector; D row-block

  const short* wgb = wbf + (size_t)gb * 9 * 4096;   // [tap][o][c]
  const short* ibase = imgt + (((size_t)gb * 66 + y) * 66 + lo) * 64 + hi * 8;

  f32x4 acc[4][4] = {};
  bf16x8 a0[4], b0[4], a1[4], b1[4];

#define LA(dst, ks) { int s_ = (ks) >> 1, h_ = (ks) & 1;                      \
    const short* p_ = wgb + (size_t)s_ * 4096 + lo * 64 + h_ * 32 + hi * 8;   \
    _Pragma("unroll") for (int m_ = 0; m_ < 4; ++m_)                          \
      dst[m_] = *(const bf16x8*)(p_ + m_ * 1024); }
#define LB(dst, ks) { int s_ = (ks) >> 1, h_ = (ks) & 1;                      \
    int dy_ = s_ / 3, dx_ = s_ - 3 * dy_;                                     \
    const short* p_ = ibase + ((size_t)dy_ * 66 + dx_) * 64 + h_ * 32;        \
    _Pragma("unroll") for (int n_ = 0; n_ < 4; ++n_)                          \
      dst[n_] = *(const bf16x8*)(p_ + n_ * 1024); }
#define MM(aa, bb) { _Pragma("unroll") for (int m_ = 0; m_ < 4; ++m_)         \
    _Pragma("unroll") for (int n_ = 0; n_ < 4; ++n_)                          \
      acc[m_][n_] = __builtin_amdgcn_mfma_f32_16x16x32_bf16(                  \
          aa[m_], bb[n_], acc[m_][n_], 0, 0, 0); }

  LA(a0, 0) LB(b0, 0)
#pragma unroll
  for (int it = 0; it < 9; ++it) {
    LA(a1, 2 * it + 1) LB(b1, 2 * it + 1)
    MM(a0, b0)
    if (it < 8) { LA(a0, 2 * it + 2) LB(b0, 2 * it + 2) }
    MM(a1, b1)
  }

  float* op = outbuf + ((size_t)b * CIN + g * GOUT) * 4096 + y * 64;
#pragma unroll
  for (int m = 0; m < 4; ++m)
#pragma unroll
    for (int j = 0; j < 4; ++j) {
      int o = m * 16 + hi * 4 + j;
      float bias = bias_f[gb * 64 + o];
#pragma unroll
      for (int n = 0; n < 4; ++n)
        op[(size_t)o * 4096 + n * 16 + lo] = acc[m][n][j] + bias;
    }
#undef LA
#undef LB
#undef MM
}

extern "C" void kernel_launch(void* const* d_in, const int* in_sizes, int n_in,
                              void* d_out, int out_size, void* d_ws, size_t ws_size,
                              hipStream_t stream) {
  const float* image = (const float*)d_in[0];
  const float* hyper = (const float*)d_in[1];
  const float* W1    = (const float*)d_in[2];
  const float* b1    = (const float*)d_in[3];
  const float* W2    = (const float*)d_in[4];
  const float* b2    = (const float*)d_in[5];
  float* out = (float*)d_out;

  float* h_t    = (float*)d_ws;                                // 74368 f32
  float* gened  = h_t + (size_t)G * HD * 8;                    // 1181696 f32
  float* bias_f = gened + (size_t)G * NBATCH * NO;             // 2048 f32
  short* wbf    = (short*)(bias_f + G * NBATCH * GOUT);        // 1179648 bf16
  short* imgt   = wbf + (size_t)G * NBATCH * 9 * 4096;         // 8921088 bf16

  const int NF4_BLOCKS = (G * NBATCH * NO4 + 255) / 256;

  k_iprep<<<dim3(66, G, NBATCH), 256, 0, stream>>>(image, imgt);
  k1_hyper_l1<<<dim3((HD + 255) / 256, G), 256, 0, stream>>>(hyper, W1, b1, h_t);
  k_init_gened<<<dim3(NF4_BLOCKS), 256, 0, stream>>>(b2, gened);
  k2_hyper_l2<<<dim3((NO4 + 255) / 256, G, DSPLIT), 256, 0, stream>>>(h_t, W2, gened);
  k_wprep<<<dim3(145, G * NBATCH), 256, 0, stream>>>(gened, wbf, bias_f);
  k3_mfma<<<dim3(16, G, NBATCH), 256, 0, stream>>>(wbf, imgt, bias_f, out);
}

// Round 8
// 313.652 us; speedup vs baseline: 17.3063x; 1.5200x over previous
//
#include <hip/hip_runtime.h>

#define G 4
#define NBATCH 8
#define HIN 128
#define HD 2324
#define NW 36864
#define NO 36928   // NW + 64 biases
#define NO4 (NO / 4)        // 9232
#define GIN 64
#define GOUT 64
#define HIMG 64
#define WIMG 64
#define CIN 256
#define DSPLIT 8
#define DCHUNK 292          // 7*292 + 280 = 2324; all chunks %4==0

typedef __attribute__((ext_vector_type(8))) short bf16x8;
typedef __attribute__((ext_vector_type(4))) float f32x4;

__device__ inline unsigned short bf16rne(float f) {
  union { float f; unsigned u; } x; x.f = f;
  unsigned r = (x.u + 0x7FFF + ((x.u >> 16) & 1)) >> 16;
  return (unsigned short)r;
}

// K1: h_t[g][d][b] = relu(b1[g][d] + sum_i hyper[b][i] * W1[g][i][d])
__global__ __launch_bounds__(256) void k1_hyper_l1(
    const float* __restrict__ hyper, const float* __restrict__ W1,
    const float* __restrict__ b1, float* __restrict__ h_t) {
  int g = blockIdx.y;
  int d = blockIdx.x * 256 + threadIdx.x;
  if (d >= HD) return;
  const float* W1g = W1 + (size_t)g * HIN * HD + d;
  float bias = b1[g * HD + d];
  float acc[NBATCH];
#pragma unroll
  for (int b = 0; b < NBATCH; ++b) acc[b] = bias;
  for (int i = 0; i < HIN; ++i) {
    float wv = W1g[(size_t)i * HD];
#pragma unroll
    for (int b = 0; b < NBATCH; ++b)
      acc[b] = fmaf(hyper[b * HIN + i], wv, acc[b]);
  }
  float4* hp = (float4*)(h_t + ((size_t)g * HD + d) * 8);
  hp[0] = make_float4(fmaxf(acc[0], 0.f), fmaxf(acc[1], 0.f),
                      fmaxf(acc[2], 0.f), fmaxf(acc[3], 0.f));
  hp[1] = make_float4(fmaxf(acc[4], 0.f), fmaxf(acc[5], 0.f),
                      fmaxf(acc[6], 0.f), fmaxf(acc[7], 0.f));
}

#define FMA_D(wv, hoff)                                   \
  {                                                       \
    _Pragma("unroll")                                     \
    for (int b = 0; b < NBATCH; ++b) {                    \
      float hv = hh[(hoff) * 8 + b];                      \
      acc[b][0] = fmaf(hv, (wv)[0], acc[b][0]);           \
      acc[b][1] = fmaf(hv, (wv)[1], acc[b][1]);           \
      acc[b][2] = fmaf(hv, (wv)[2], acc[b][2]);           \
      acc[b][3] = fmaf(hv, (wv)[3], acc[b][3]);           \
    }                                                     \
  }

// K2: partial[ds][gb][o] = sum_{d in chunk ds} h[g][b][d] * W2[g][d][o]
// Non-atomic (contention-free) split-K; nontemporal W2 stream (zero reuse).
__global__ __launch_bounds__(256) void k2_hyper_l2(
    const float* __restrict__ h_t, const float* __restrict__ W2,
    float* __restrict__ partial) {
  int g = blockIdx.y, ds = blockIdx.z;
  int o4 = blockIdx.x * 256 + threadIdx.x;
  bool active = (o4 < NO4);
  if (!active) o4 = NO4 - 1;
  const f32x4* W2g = (const f32x4*)(W2 + (size_t)g * HD * NO) + o4;
  const float* hg = h_t + (size_t)g * HD * 8;
  int d0 = ds * DCHUNK;
  int d1 = d0 + DCHUNK; if (d1 > HD) d1 = HD;
  int nd = d1 - d0;                        // multiple of 4

  f32x4 acc[NBATCH] = {};
  const size_t WS = NO4;
  const f32x4* Wp = W2g + (size_t)d0 * WS;
  f32x4 w0 = __builtin_nontemporal_load(Wp);
  f32x4 w1 = __builtin_nontemporal_load(Wp + WS);
  f32x4 w2 = __builtin_nontemporal_load(Wp + 2 * WS);
  f32x4 w3 = __builtin_nontemporal_load(Wp + 3 * WS);
  int dd = 0;
  for (; dd < nd - 4; dd += 4) {
    const f32x4* Wn = Wp + (size_t)(dd + 4) * WS;
    f32x4 n0 = __builtin_nontemporal_load(Wn);
    f32x4 n1 = __builtin_nontemporal_load(Wn + WS);
    f32x4 n2 = __builtin_nontemporal_load(Wn + 2 * WS);
    f32x4 n3 = __builtin_nontemporal_load(Wn + 3 * WS);
    const float* hh = hg + (size_t)(d0 + dd) * 8;   // 32 contiguous f32
    FMA_D(w0, 0) FMA_D(w1, 1) FMA_D(w2, 2) FMA_D(w3, 3)
    w0 = n0; w1 = n1; w2 = n2; w3 = n3;
  }
  {
    const float* hh = hg + (size_t)(d0 + dd) * 8;
    FMA_D(w0, 0) FMA_D(w1, 1) FMA_D(w2, 2) FMA_D(w3, 3)
  }

  if (active) {
    f32x4* pout = (f32x4*)partial + ((size_t)ds * G * NBATCH + g * NBATCH) * NO4 + o4;
#pragma unroll
    for (int b = 0; b < NBATCH; ++b) pout[(size_t)b * NO4] = acc[b];
  }
}

// wprep: wbf[gb][k][o][c] = bf16(b2[g][f] + sum_ds partial[ds][gb][f]),
// f = o*576 + c*9 + k. Block x==144: bias_f[gb][o] (f = NW + o).
__global__ __launch_bounds__(256) void k_wprep(
    const float* __restrict__ partial, const float* __restrict__ b2,
    short* __restrict__ wbf, float* __restrict__ bias_f) {
  int gb = blockIdx.y;
  int g = gb >> 3;
  if (blockIdx.x == 144) {
    int o = threadIdx.x;
    if (o < GOUT) {
      float s = b2[(size_t)g * NO + NW + o];
#pragma unroll
      for (int ds = 0; ds < DSPLIT; ++ds)
        s += partial[((size_t)ds * G * NBATCH + gb) * NO + NW + o];
      bias_f[gb * GOUT + o] = s;
    }
    return;
  }
  int q = blockIdx.x * 256 + threadIdx.x;     // [0, 36864)
  int c = q & 63, rest = q >> 6;
  int o = rest & 63, k = rest >> 6;           // k 0..8
  int f = o * 576 + c * 9 + k;
  float s = b2[(size_t)g * NO + f];
#pragma unroll
  for (int ds = 0; ds < DSPLIT; ++ds)
    s += partial[((size_t)ds * G * NBATCH + gb) * NO + f];
  wbf[(size_t)gb * 9 * 4096 + q] = (short)bf16rne(s);  // q == k*4096+o*64+c
}

// iprep: imgt[gb][y+1][x+1][c] = bf16(image[b][g*64+c][y][x]);
// halo rows/cols written in-kernel. grid.x = 66 dest rows.
__global__ __launch_bounds__(256) void k_iprep(
    const float* __restrict__ image, short* __restrict__ imgt) {
  int row = blockIdx.x;                       // dest row 0..65
  int g = blockIdx.y, b = blockIdx.z;
  int gb = g * NBATCH + b;
  int tid = threadIdx.x;
  short* rowp = imgt + ((size_t)gb * 66 + row) * 66 * 64;
  if (row == 0 || row == 65) {                // top/bottom halo row
    uint4 z = {0, 0, 0, 0};
    uint4* p = (uint4*)rowp;                  // 528 uint4
#pragma unroll
    for (int i = 0; i < 3; ++i) {
      int idx = tid + i * 256;
      if (idx < 528) p[idx] = z;
    }
    return;
  }
  int y = row - 1;
  __shared__ float lds[64 * 65];
  int p = tid & 63, cg = tid >> 6;
#pragma unroll
  for (int i = 0; i < 16; ++i) {
    int c = cg * 16 + i;
    lds[p * 65 + c] = image[((size_t)b * CIN + g * GIN + c) * 4096 + y * 64 + p];
  }
  __syncthreads();
  int p2 = tid >> 2, cq = tid & 3;
  unsigned short tmp[16];
#pragma unroll
  for (int i = 0; i < 16; ++i) tmp[i] = bf16rne(lds[p2 * 65 + cq * 16 + i]);
  short* dst = rowp + (p2 + 1) * 64 + cq * 16;
  *(uint4*)dst = *(uint4*)&tmp[0];
  *(uint4*)(dst + 8) = *(uint4*)&tmp[8];
  if (tid < 16) {                             // side halo col 0
    ((uint2*)rowp)[tid] = make_uint2(0, 0);
  } else if (tid < 32) {                      // side halo col 65
    ((uint2*)(rowp + 65 * 64))[tid - 16] = make_uint2(0, 0);
  }
}

// K3-MFMA: 32 GEMMs M=64,N=4096,K=576 as 9 shifts x 2 c-tiles of
// 16x16x32 bf16 MFMA. Wave = one image row y; 4x4 C-frags; 1-deep prefetch.
__global__ __launch_bounds__(256) void k3_mfma(
    const short* __restrict__ wbf, const short* __restrict__ imgt,
    const float* __restrict__ bias_f, float* __restrict__ outbuf) {
  int g = blockIdx.y, b = blockIdx.z;
  int gb = g * NBATCH + b;
  int ygrp = blockIdx.x & 15;
  int tid = threadIdx.x;
  int w = tid >> 6, l = tid & 63;
  int y = ygrp * 4 + w;
  int lo = l & 15;   // A row (o), B col (x), D col
  int hi = l >> 4;   // k-chunk selector; D row-block

  const short* wgb = wbf + (size_t)gb * 9 * 4096;   // [tap][o][c]
  const short* ibase = imgt + (((size_t)gb * 66 + y) * 66 + lo) * 64 + hi * 8;

  f32x4 acc[4][4] = {};
  bf16x8 a0[4], b0[4], a1[4], b1[4];

#define LA(dst, ks) { int s_ = (ks) >> 1, h_ = (ks) & 1;                      \
    const short* p_ = wgb + (size_t)s_ * 4096 + lo * 64 + h_ * 32 + hi * 8;   \
    _Pragma("unroll") for (int m_ = 0; m_ < 4; ++m_)                          \
      dst[m_] = *(const bf16x8*)(p_ + m_ * 1024); }
#define LB(dst, ks) { int s_ = (ks) >> 1, h_ = (ks) & 1;                      \
    int dy_ = s_ / 3, dx_ = s_ - 3 * dy_;                                     \
    const short* p_ = ibase + ((size_t)dy_ * 66 + dx_) * 64 + h_ * 32;        \
    _Pragma("unroll") for (int n_ = 0; n_ < 4; ++n_)                          \
      dst[n_] = *(const bf16x8*)(p_ + n_ * 1024); }
#define MM(aa, bb) { _Pragma("unroll") for (int m_ = 0; m_ < 4; ++m_)         \
    _Pragma("unroll") for (int n_ = 0; n_ < 4; ++n_)                          \
      acc[m_][n_] = __builtin_amdgcn_mfma_f32_16x16x32_bf16(                  \
          aa[m_], bb[n_], acc[m_][n_], 0, 0, 0); }

  LA(a0, 0) LB(b0, 0)
#pragma unroll
  for (int it = 0; it < 9; ++it) {
    LA(a1, 2 * it + 1) LB(b1, 2 * it + 1)
    MM(a0, b0)
    if (it < 8) { LA(a0, 2 * it + 2) LB(b0, 2 * it + 2) }
    MM(a1, b1)
  }

  float* op = outbuf + ((size_t)b * CIN + g * GOUT) * 4096 + y * 64;
#pragma unroll
  for (int m = 0; m < 4; ++m)
#pragma unroll
    for (int j = 0; j < 4; ++j) {
      int o = m * 16 + hi * 4 + j;
      float bias = bias_f[gb * 64 + o];
#pragma unroll
      for (int n = 0; n < 4; ++n)
        op[(size_t)o * 4096 + n * 16 + lo] = acc[m][n][j] + bias;
    }
#undef LA
#undef LB
#undef MM
}

extern "C" void kernel_launch(void* const* d_in, const int* in_sizes, int n_in,
                              void* d_out, int out_size, void* d_ws, size_t ws_size,
                              hipStream_t stream) {
  const float* image = (const float*)d_in[0];
  const float* hyper = (const float*)d_in[1];
  const float* W1    = (const float*)d_in[2];
  const float* b1    = (const float*)d_in[3];
  const float* W2    = (const float*)d_in[4];
  const float* b2    = (const float*)d_in[5];
  float* out = (float*)d_out;

  float* h_t     = (float*)d_ws;                               // 74368 f32
  float* bias_f  = h_t + (size_t)G * HD * 8;                   // 2048 f32
  float* partial = bias_f + G * NBATCH * GOUT;                 // 8*32*NO f32
  short* wbf     = (short*)(partial + (size_t)DSPLIT * G * NBATCH * NO);
  short* imgt    = wbf + (size_t)G * NBATCH * 9 * 4096;        // 8921088 bf16

  k_iprep<<<dim3(66, G, NBATCH), 256, 0, stream>>>(image, imgt);
  k1_hyper_l1<<<dim3((HD + 255) / 256, G), 256, 0, stream>>>(hyper, W1, b1, h_t);
  k2_hyper_l2<<<dim3((NO4 + 255) / 256, G, DSPLIT), 256, 0, stream>>>(h_t, W2, partial);
  k_wprep<<<dim3(145, G * NBATCH), 256, 0, stream>>>(partial, b2, wbf, bias_f);
  k3_mfma<<<dim3(16, G, NBATCH), 256, 0, stream>>>(wbf, imgt, bias_f, out);
}